// Round 15
// baseline (199.765 us; speedup 1.0000x reference)
//
#include <hip/hip_runtime.h>
#include <hip/hip_fp16.h>

// ---------------------------------------------------------------------------
// GCN pipeline v15: v14 + 16-edge/round gather (4 lanes/edge, 2 independent
// 16B loads -> most nodes single-round) + vectorized fill. 11 dispatches.
// N=50000 nodes, E=800000 edges, H=F=64, G=512 graphs, C=10 classes
// ---------------------------------------------------------------------------

using half8 = __attribute__((ext_vector_type(8))) _Float16;
using f32x4 = __attribute__((ext_vector_type(4))) float;

// Single-block: detect whether mask is bytes (some word >1) or int32 0/1.
__global__ void k_detect(const unsigned int* __restrict__ m, int n_ints,
                         int* __restrict__ flag) {
  __shared__ int found;
  if (threadIdx.x == 0) found = 0;
  __syncthreads();
  int loc = 0;
  for (int i = threadIdx.x; i < n_ints; i += blockDim.x)
    if (m[i] > 1u) loc = 1;
  if (loc) found = 1;
  __syncthreads();
  if (threadIdx.x == 0) *flag = found;
}

// maskf + zero cnt + init gs/ge + W1/2/3 -> MFMA-swizzled fp16 fragments.
__global__ void k_prep(const void* __restrict__ mraw, const int* __restrict__ flag,
                       float* __restrict__ maskf, int* __restrict__ cnt,
                       int* __restrict__ gs, int* __restrict__ ge,
                       const float* __restrict__ W1, const float* __restrict__ W2,
                       const float* __restrict__ W3, __half* __restrict__ Wsw,
                       int N, int G) {
  int idx = blockIdx.x * blockDim.x + threadIdx.x;
  if (idx < 3 * 4096) {
    const int layer = idx >> 12;
    const int rem = idx & 4095;
    const int f = rem >> 9;
    const int l = (rem >> 3) & 63;
    const int j = rem & 7;
    const int k = (f >> 2) * 32 + ((l >> 4) << 3) + j;
    const int c = ((f & 3) << 4) + (l & 15);
    const float* Wl = (layer == 0) ? W1 : (layer == 1) ? W2 : W3;
    Wsw[idx] = __float2half_rn(Wl[k * 64 + c]);
  }
  if (idx < G) { gs[idx] = 0x7fffffff; ge[idx] = -1; }
  if (idx < N) {
    float v;
    if (*flag) v = (float)((const unsigned char*)mraw)[idx];
    else       v = (float)((const int*)mraw)[idx];
    maskf[idx] = v;
    cnt[idx] = 0;
  }
}

// One-pass bucket CSR, 2 edges/thread: csr[d*64 + slot] = s.
__global__ void k_fill(const int* __restrict__ src, const int* __restrict__ dst,
                       const float* __restrict__ maskf, int* __restrict__ cnt,
                       int* __restrict__ csr, int E) {
  int e2 = blockIdx.x * blockDim.x + threadIdx.x;
  int e = e2 * 2;
  if (e >= E) return;
  if (e + 1 < E) {
    const int2 s2 = *(const int2*)&src[e];
    const int2 d2 = *(const int2*)&dst[e];
    if (maskf[s2.x] != 0.f && maskf[d2.x] != 0.f) {
      int p = atomicAdd(&cnt[d2.x], 1);
      if (p < 63) csr[(long)d2.x * 64 + p] = s2.x;
    }
    if (maskf[s2.y] != 0.f && maskf[d2.y] != 0.f) {
      int p = atomicAdd(&cnt[d2.y], 1);
      if (p < 63) csr[(long)d2.y * 64 + p] = s2.y;
    }
  } else {
    const int s = src[e], d = dst[e];
    if (maskf[s] != 0.f && maskf[d] != 0.f) {
      int p = atomicAdd(&cnt[d], 1);
      if (p < 63) csr[(long)d * 64 + p] = s;
    }
  }
}

// dinv + self-loop slot + meta=(n, dinv_bits) + per-graph bounds (sorted batch).
__global__ void k_dinvself(const int* __restrict__ cnt, const float* __restrict__ maskf,
                           float* __restrict__ dinv, int2* __restrict__ meta,
                           int* __restrict__ csr, const int* __restrict__ batch,
                           int* __restrict__ gs, int* __restrict__ ge, int N) {
  int i = blockIdx.x * blockDim.x + threadIdx.x;
  if (i >= N) return;
  int c = min(cnt[i], 63);
  float mk = maskf[i];
  float dsum = (float)c + mk;
  float di = (dsum > 0.f) ? rsqrtf(dsum) : 0.f;
  dinv[i] = di;
  int n;
  if (mk != 0.f) {
    csr[(long)i * 64 + c] = i;   // self-loop entry
    n = c + 1;
  } else {
    n = 0;
  }
  meta[i] = make_int2(n, __float_as_int(di));
  int b = batch[i];
  if (i == 0 || batch[i - 1] != b) gs[b] = i;
  if (i == N - 1 || batch[i + 1] != b) ge[b] = i;
}

// T = A @ W via MFMA 16x16x32 fp16. Wave per 16-row tile (grid-stride).
template <bool F32IN>
__global__ __launch_bounds__(256) void k_gemm_mfma(const void* __restrict__ A,
                                                   const __half* __restrict__ Wsw,
                                                   __half* __restrict__ T, int N) {
  const int lane = threadIdx.x & 63;
  const int wid = threadIdx.x >> 6;
  half8 bfrag[8];
#pragma unroll
  for (int f = 0; f < 8; ++f)
    bfrag[f] = *(const half8*)&Wsw[f * 512 + lane * 8];
  const int tiles = (N + 15) >> 4;
  const int arow_off = ((lane >> 4) << 3);
  for (int t = blockIdx.x * 4 + wid; t < tiles; t += gridDim.x * 4) {
    const int rt = t << 4;
    int arow = rt + (lane & 15);
    if (arow >= N) arow = N - 1;
    half8 a0, a1;
    if (F32IN) {
      const float* Af = (const float*)A;
      const float4 f0 = *(const float4*)&Af[(long)arow * 64 + arow_off];
      const float4 f1 = *(const float4*)&Af[(long)arow * 64 + arow_off + 4];
      const float4 f2 = *(const float4*)&Af[(long)arow * 64 + 32 + arow_off];
      const float4 f3 = *(const float4*)&Af[(long)arow * 64 + 32 + arow_off + 4];
      a0[0] = (_Float16)f0.x; a0[1] = (_Float16)f0.y;
      a0[2] = (_Float16)f0.z; a0[3] = (_Float16)f0.w;
      a0[4] = (_Float16)f1.x; a0[5] = (_Float16)f1.y;
      a0[6] = (_Float16)f1.z; a0[7] = (_Float16)f1.w;
      a1[0] = (_Float16)f2.x; a1[1] = (_Float16)f2.y;
      a1[2] = (_Float16)f2.z; a1[3] = (_Float16)f2.w;
      a1[4] = (_Float16)f3.x; a1[5] = (_Float16)f3.y;
      a1[6] = (_Float16)f3.z; a1[7] = (_Float16)f3.w;
    } else {
      const __half* Ah = (const __half*)A;
      a0 = *(const half8*)&Ah[(long)arow * 64 + arow_off];
      a1 = *(const half8*)&Ah[(long)arow * 64 + 32 + arow_off];
    }
    f32x4 acc0 = {0.f, 0.f, 0.f, 0.f};
    f32x4 acc1 = {0.f, 0.f, 0.f, 0.f};
    f32x4 acc2 = {0.f, 0.f, 0.f, 0.f};
    f32x4 acc3 = {0.f, 0.f, 0.f, 0.f};
    acc0 = __builtin_amdgcn_mfma_f32_16x16x32_f16(a0, bfrag[0], acc0, 0, 0, 0);
    acc1 = __builtin_amdgcn_mfma_f32_16x16x32_f16(a0, bfrag[1], acc1, 0, 0, 0);
    acc2 = __builtin_amdgcn_mfma_f32_16x16x32_f16(a0, bfrag[2], acc2, 0, 0, 0);
    acc3 = __builtin_amdgcn_mfma_f32_16x16x32_f16(a0, bfrag[3], acc3, 0, 0, 0);
    acc0 = __builtin_amdgcn_mfma_f32_16x16x32_f16(a1, bfrag[4], acc0, 0, 0, 0);
    acc1 = __builtin_amdgcn_mfma_f32_16x16x32_f16(a1, bfrag[5], acc1, 0, 0, 0);
    acc2 = __builtin_amdgcn_mfma_f32_16x16x32_f16(a1, bfrag[6], acc2, 0, 0, 0);
    acc3 = __builtin_amdgcn_mfma_f32_16x16x32_f16(a1, bfrag[7], acc3, 0, 0, 0);
    const int col = lane & 15;
    const int mbase = rt + ((lane >> 4) << 2);
#pragma unroll
    for (int reg = 0; reg < 4; ++reg) {
      const int r = mbase + reg;
      if (r < N) {
        __half* o = T + (long)r * 64 + col;
        o[0]  = __float2half_rn(acc0[reg]);
        o[16] = __float2half_rn(acc1[reg]);
        o[32] = __float2half_rn(acc2[reg]);
        o[48] = __float2half_rn(acc3[reg]);
      }
    }
  }
}

// H[d][:] = relu( sum_{slots} dinv[s]*dinv[d] * T[s][:] + b )
// Wave per kept node; 16 edges/round via 4-lane groups (2x16B loads/lane) so
// mean-degree-11 nodes finish in ONE round. Direct-broadcast CSR + dinv.
template <bool HALFOUT>
__global__ __launch_bounds__(256) void k_agg(const __half* __restrict__ Th,
                                             const int2* __restrict__ meta,
                                             const int* __restrict__ csr,
                                             const float* __restrict__ dinv,
                                             const float* __restrict__ b,
                                             void* __restrict__ H, int N) {
  const int lane = threadIdx.x & 63;
  const int wid = threadIdx.x >> 6;
  const int grp = lane >> 2;   // edge slot within the round (16 slots)
  const int q = lane & 3;      // column group: cols 16q..16q+15
  const __half* __restrict__ Tq = Th + q * 16;
  const float4 bq0 = *(const float4*)&b[q * 16];
  const float4 bq1 = *(const float4*)&b[q * 16 + 4];
  const float4 bq2 = *(const float4*)&b[q * 16 + 8];
  const float4 bq3 = *(const float4*)&b[q * 16 + 12];

  for (int d = blockIdx.x * 4 + wid; d < N; d += gridDim.x * 4) {
    const int2 mt = meta[d];
    const int n = mt.x;
    if (n == 0) continue;  // dropped node
    const float dinv_d = __int_as_float(mt.y);
    const int* __restrict__ cb = csr + (long)d * 64;
    float4 a0 = make_float4(0.f, 0.f, 0.f, 0.f);
    float4 a1 = make_float4(0.f, 0.f, 0.f, 0.f);
    float4 a2 = make_float4(0.f, 0.f, 0.f, 0.f);
    float4 a3 = make_float4(0.f, 0.f, 0.f, 0.f);
    const int rounds = (n + 15) & ~15;
#pragma unroll 2
    for (int i = grp; i < rounds; i += 16) {
      const int idx = min(i, n - 1);      // clamp: overflow slots re-read last
      const int s = cb[idx];
      const float4 raw0 = *(const float4*)&Tq[(long)s * 64];      // cols 16q..+7
      const float4 raw1 = *(const float4*)&Tq[(long)s * 64 + 8];  // cols +8..+15
      const float w = (i < n) ? dinv[s] * dinv_d : 0.f;
      const __half2* h0 = (const __half2*)&raw0;
      const __half2* h1 = (const __half2*)&raw1;
      float2 f;
      f = __half22float2(h0[0]); a0.x = fmaf(f.x, w, a0.x); a0.y = fmaf(f.y, w, a0.y);
      f = __half22float2(h0[1]); a0.z = fmaf(f.x, w, a0.z); a0.w = fmaf(f.y, w, a0.w);
      f = __half22float2(h0[2]); a1.x = fmaf(f.x, w, a1.x); a1.y = fmaf(f.y, w, a1.y);
      f = __half22float2(h0[3]); a1.z = fmaf(f.x, w, a1.z); a1.w = fmaf(f.y, w, a1.w);
      f = __half22float2(h1[0]); a2.x = fmaf(f.x, w, a2.x); a2.y = fmaf(f.y, w, a2.y);
      f = __half22float2(h1[1]); a2.z = fmaf(f.x, w, a2.z); a2.w = fmaf(f.y, w, a2.w);
      f = __half22float2(h1[2]); a3.x = fmaf(f.x, w, a3.x); a3.y = fmaf(f.y, w, a3.y);
      f = __half22float2(h1[3]); a3.z = fmaf(f.x, w, a3.z); a3.w = fmaf(f.y, w, a3.w);
    }
    // butterfly across the 16 edge slots (lanes sharing q share columns)
#pragma unroll
    for (int m = 4; m <= 32; m <<= 1) {
      a0.x += __shfl_xor(a0.x, m); a0.y += __shfl_xor(a0.y, m);
      a0.z += __shfl_xor(a0.z, m); a0.w += __shfl_xor(a0.w, m);
      a1.x += __shfl_xor(a1.x, m); a1.y += __shfl_xor(a1.y, m);
      a1.z += __shfl_xor(a1.z, m); a1.w += __shfl_xor(a1.w, m);
      a2.x += __shfl_xor(a2.x, m); a2.y += __shfl_xor(a2.y, m);
      a2.z += __shfl_xor(a2.z, m); a2.w += __shfl_xor(a2.w, m);
      a3.x += __shfl_xor(a3.x, m); a3.y += __shfl_xor(a3.y, m);
      a3.z += __shfl_xor(a3.z, m); a3.w += __shfl_xor(a3.w, m);
    }
    if (grp == 0) {
      const float r0 = fmaxf(a0.x + bq0.x, 0.f);
      const float r1 = fmaxf(a0.y + bq0.y, 0.f);
      const float r2 = fmaxf(a0.z + bq0.z, 0.f);
      const float r3 = fmaxf(a0.w + bq0.w, 0.f);
      const float r4 = fmaxf(a1.x + bq1.x, 0.f);
      const float r5 = fmaxf(a1.y + bq1.y, 0.f);
      const float r6 = fmaxf(a1.z + bq1.z, 0.f);
      const float r7 = fmaxf(a1.w + bq1.w, 0.f);
      const float r8 = fmaxf(a2.x + bq2.x, 0.f);
      const float r9 = fmaxf(a2.y + bq2.y, 0.f);
      const float rA = fmaxf(a2.z + bq2.z, 0.f);
      const float rB = fmaxf(a2.w + bq2.w, 0.f);
      const float rC = fmaxf(a3.x + bq3.x, 0.f);
      const float rD = fmaxf(a3.y + bq3.y, 0.f);
      const float rE = fmaxf(a3.z + bq3.z, 0.f);
      const float rF = fmaxf(a3.w + bq3.w, 0.f);
      if (HALFOUT) {
        __half2* o = (__half2*)((__half*)H + (long)d * 64 + q * 16);
        o[0] = __floats2half2_rn(r0, r1);
        o[1] = __floats2half2_rn(r2, r3);
        o[2] = __floats2half2_rn(r4, r5);
        o[3] = __floats2half2_rn(r6, r7);
        o[4] = __floats2half2_rn(r8, r9);
        o[5] = __floats2half2_rn(rA, rB);
        o[6] = __floats2half2_rn(rC, rD);
        o[7] = __floats2half2_rn(rE, rF);
      } else {
        float* o = (float*)H + (long)d * 64 + q * 16;
        *(float4*)o = make_float4(r0, r1, r2, r3);
        *(float4*)(o + 4) = make_float4(r4, r5, r6, r7);
        *(float4*)(o + 8) = make_float4(r8, r9, rA, rB);
        *(float4*)(o + 12) = make_float4(rC, rD, rE, rF);
      }
    }
  }
}

// Fused: per-graph max-pool over kept nodes -> MLP head -> out[grp][:]
__global__ __launch_bounds__(256) void k_pool_head(
    const float* __restrict__ H, const float* __restrict__ maskf,
    const int* __restrict__ gs, const int* __restrict__ ge,
    const float* __restrict__ fw1, const float* __restrict__ fb1,
    const float* __restrict__ fw2, const float* __restrict__ fb2,
    float* __restrict__ out, int N, int C) {
  __shared__ float sP[4][64];
  __shared__ float sg[64];
  __shared__ float sg2[64];
  const int grp = blockIdx.x;
  const int lane = threadIdx.x & 63, wid = threadIdx.x >> 6;
  const int s = gs[grp], e = ge[grp];
  float v = 0.f;
  if (s <= e) {
    for (int i = s + wid; i <= e; i += 4)
      if (maskf[i] != 0.f) v = fmaxf(v, H[(long)i * 64 + lane]);
  }
  sP[wid][lane] = v;
  __syncthreads();
  if (wid == 0)
    sg[lane] = fmaxf(fmaxf(sP[0][lane], sP[1][lane]), fmaxf(sP[2][lane], sP[3][lane]));
  __syncthreads();
  if (threadIdx.x < 64) {
    const int f = threadIdx.x;
    float acc = fb1[f];
#pragma unroll 8
    for (int k = 0; k < 64; ++k) acc = fmaf(sg[k], fw1[k * 64 + f], acc);
    sg2[f] = fmaxf(acc, 0.f);
  }
  __syncthreads();
  if (threadIdx.x < C) {
    const int c = threadIdx.x;
    float acc = fb2[c];
#pragma unroll 8
    for (int k = 0; k < 64; ++k) acc = fmaf(sg2[k], fw2[k * C + c], acc);
    out[grp * C + c] = acc;
  }
}

extern "C" void kernel_launch(void* const* d_in, const int* in_sizes, int n_in,
                              void* d_out, int out_size, void* d_ws, size_t ws_size,
                              hipStream_t stream) {
  const float* x    = (const float*)d_in[0];
  const int*   ei   = (const int*)d_in[1];
  const int*   batch= (const int*)d_in[2];
  const void*  mraw = d_in[3];
  const float* W1   = (const float*)d_in[4];
  const float* b1   = (const float*)d_in[5];
  const float* W2   = (const float*)d_in[6];
  const float* b2   = (const float*)d_in[7];
  const float* W3   = (const float*)d_in[8];
  const float* b3   = (const float*)d_in[9];
  const float* fw1  = (const float*)d_in[10];
  const float* fb1  = (const float*)d_in[11];
  const float* fw2  = (const float*)d_in[12];
  const float* fb2  = (const float*)d_in[13];
  float* out = (float*)d_out;

  const int N = in_sizes[0] / 64;
  const int E = in_sizes[1] / 2;
  const int C = in_sizes[13];
  const int* src = ei;
  const int* dst = ei + E;
  const int G = out_size / C;

  char* ws = (char*)d_ws;
  size_t off_b = 0;
  auto alloc = [&](size_t bytes) -> void* {
    void* p = ws + off_b;
    off_b += (bytes + 255) & ~(size_t)255;
    return p;
  };
  int*    flag   = (int*)alloc(sizeof(int));
  float*  maskf  = (float*)alloc((size_t)N * 4);
  int*    cnt    = (int*)alloc((size_t)N * 4);
  float*  dinv   = (float*)alloc((size_t)N * 4);
  int2*   meta   = (int2*)alloc((size_t)N * 8);
  int*    gs     = (int*)alloc((size_t)G * 4);
  int*    ge     = (int*)alloc((size_t)G * 4);
  int*    csr    = (int*)alloc((size_t)N * 64 * 4);   // 64 slots/node
  __half* Wsw    = (__half*)alloc(3 * 4096 * 2);
  __half* T      = (__half*)alloc((size_t)N * 64 * 2);
  __half* H1h    = (__half*)alloc((size_t)N * 64 * 2);
  __half* H2h    = (__half*)alloc((size_t)N * 64 * 2);
  float*  H3     = (float*)alloc((size_t)N * 64 * 4);
  (void)ws_size;

  const int nb = (N + 255) / 256;

  k_detect<<<1, 1024, 0, stream>>>((const unsigned int*)mraw, N / 4, flag);
  k_prep<<<nb, 256, 0, stream>>>(mraw, flag, maskf, cnt, gs, ge,
                                 W1, W2, W3, Wsw, N, G);

  const int gemm_blocks = 512;
  const int agg_blocks = 2048;

  // layer-1 GEMM first: depends only on prep (x read directly as f32)
  k_gemm_mfma<true><<<gemm_blocks, 256, 0, stream>>>(x, Wsw, T, N);

  k_fill<<<(E / 2 + 255) / 256, 256, 0, stream>>>(src, dst, maskf, cnt, csr, E);
  k_dinvself<<<nb, 256, 0, stream>>>(cnt, maskf, dinv, meta, csr, batch, gs, ge, N);

  // layer 1 aggregate
  k_agg<true><<<agg_blocks, 256, 0, stream>>>(T, meta, csr, dinv, b1, H1h, N);
  // layer 2
  k_gemm_mfma<false><<<gemm_blocks, 256, 0, stream>>>(H1h, Wsw + 4096, T, N);
  k_agg<true><<<agg_blocks, 256, 0, stream>>>(T, meta, csr, dinv, b2, H2h, N);
  // layer 3
  k_gemm_mfma<false><<<gemm_blocks, 256, 0, stream>>>(H2h, Wsw + 8192, T, N);
  k_agg<false><<<agg_blocks, 256, 0, stream>>>(T, meta, csr, dinv, b3, H3, N);

  k_pool_head<<<G, 256, 0, stream>>>(H3, maskf, gs, ge, fw1, fb1, fw2, fb2, out, N, C);
}

// Round 16
// 146.847 us; speedup vs baseline: 1.3604x; 1.3604x over previous
//
#include <hip/hip_runtime.h>
#include <hip/hip_fp16.h>

// ---------------------------------------------------------------------------
// GCN pipeline v16: v14 base (8-slot gather, bucket CSR) + 2-node-per-wave
// agg (2x independent gather chains) + vectorized fill. 11 dispatches.
// N=50000 nodes, E=800000 edges, H=F=64, G=512 graphs, C=10 classes
// ---------------------------------------------------------------------------

using half8 = __attribute__((ext_vector_type(8))) _Float16;
using f32x4 = __attribute__((ext_vector_type(4))) float;

// Single-block: detect whether mask is bytes (some word >1) or int32 0/1.
__global__ void k_detect(const unsigned int* __restrict__ m, int n_ints,
                         int* __restrict__ flag) {
  __shared__ int found;
  if (threadIdx.x == 0) found = 0;
  __syncthreads();
  int loc = 0;
  for (int i = threadIdx.x; i < n_ints; i += blockDim.x)
    if (m[i] > 1u) loc = 1;
  if (loc) found = 1;
  __syncthreads();
  if (threadIdx.x == 0) *flag = found;
}

// maskf + zero cnt + init gs/ge + W1/2/3 -> MFMA-swizzled fp16 fragments.
__global__ void k_prep(const void* __restrict__ mraw, const int* __restrict__ flag,
                       float* __restrict__ maskf, int* __restrict__ cnt,
                       int* __restrict__ gs, int* __restrict__ ge,
                       const float* __restrict__ W1, const float* __restrict__ W2,
                       const float* __restrict__ W3, __half* __restrict__ Wsw,
                       int N, int G) {
  int idx = blockIdx.x * blockDim.x + threadIdx.x;
  if (idx < 3 * 4096) {
    const int layer = idx >> 12;
    const int rem = idx & 4095;
    const int f = rem >> 9;
    const int l = (rem >> 3) & 63;
    const int j = rem & 7;
    const int k = (f >> 2) * 32 + ((l >> 4) << 3) + j;
    const int c = ((f & 3) << 4) + (l & 15);
    const float* Wl = (layer == 0) ? W1 : (layer == 1) ? W2 : W3;
    Wsw[idx] = __float2half_rn(Wl[k * 64 + c]);
  }
  if (idx < G) { gs[idx] = 0x7fffffff; ge[idx] = -1; }
  if (idx < N) {
    float v;
    if (*flag) v = (float)((const unsigned char*)mraw)[idx];
    else       v = (float)((const int*)mraw)[idx];
    maskf[idx] = v;
    cnt[idx] = 0;
  }
}

// One-pass bucket CSR, 2 edges/thread: csr[d*64 + slot] = s.
__global__ void k_fill(const int* __restrict__ src, const int* __restrict__ dst,
                       const float* __restrict__ maskf, int* __restrict__ cnt,
                       int* __restrict__ csr, int E) {
  int e2 = blockIdx.x * blockDim.x + threadIdx.x;
  int e = e2 * 2;
  if (e >= E) return;
  if (e + 1 < E) {
    const int2 s2 = *(const int2*)&src[e];
    const int2 d2 = *(const int2*)&dst[e];
    if (maskf[s2.x] != 0.f && maskf[d2.x] != 0.f) {
      int p = atomicAdd(&cnt[d2.x], 1);
      if (p < 63) csr[(long)d2.x * 64 + p] = s2.x;
    }
    if (maskf[s2.y] != 0.f && maskf[d2.y] != 0.f) {
      int p = atomicAdd(&cnt[d2.y], 1);
      if (p < 63) csr[(long)d2.y * 64 + p] = s2.y;
    }
  } else {
    const int s = src[e], d = dst[e];
    if (maskf[s] != 0.f && maskf[d] != 0.f) {
      int p = atomicAdd(&cnt[d], 1);
      if (p < 63) csr[(long)d * 64 + p] = s;
    }
  }
}

// dinv + self-loop slot + meta=(n, dinv_bits) + per-graph bounds (sorted batch).
__global__ void k_dinvself(const int* __restrict__ cnt, const float* __restrict__ maskf,
                           float* __restrict__ dinv, int2* __restrict__ meta,
                           int* __restrict__ csr, const int* __restrict__ batch,
                           int* __restrict__ gs, int* __restrict__ ge, int N) {
  int i = blockIdx.x * blockDim.x + threadIdx.x;
  if (i >= N) return;
  int c = min(cnt[i], 63);
  float mk = maskf[i];
  float dsum = (float)c + mk;
  float di = (dsum > 0.f) ? rsqrtf(dsum) : 0.f;
  dinv[i] = di;
  int n;
  if (mk != 0.f) {
    csr[(long)i * 64 + c] = i;   // self-loop entry
    n = c + 1;
  } else {
    n = 0;
  }
  meta[i] = make_int2(n, __float_as_int(di));
  int b = batch[i];
  if (i == 0 || batch[i - 1] != b) gs[b] = i;
  if (i == N - 1 || batch[i + 1] != b) ge[b] = i;
}

// T = A @ W via MFMA 16x16x32 fp16. Wave per 16-row tile (grid-stride).
template <bool F32IN>
__global__ __launch_bounds__(256) void k_gemm_mfma(const void* __restrict__ A,
                                                   const __half* __restrict__ Wsw,
                                                   __half* __restrict__ T, int N) {
  const int lane = threadIdx.x & 63;
  const int wid = threadIdx.x >> 6;
  half8 bfrag[8];
#pragma unroll
  for (int f = 0; f < 8; ++f)
    bfrag[f] = *(const half8*)&Wsw[f * 512 + lane * 8];
  const int tiles = (N + 15) >> 4;
  const int arow_off = ((lane >> 4) << 3);
  for (int t = blockIdx.x * 4 + wid; t < tiles; t += gridDim.x * 4) {
    const int rt = t << 4;
    int arow = rt + (lane & 15);
    if (arow >= N) arow = N - 1;
    half8 a0, a1;
    if (F32IN) {
      const float* Af = (const float*)A;
      const float4 f0 = *(const float4*)&Af[(long)arow * 64 + arow_off];
      const float4 f1 = *(const float4*)&Af[(long)arow * 64 + arow_off + 4];
      const float4 f2 = *(const float4*)&Af[(long)arow * 64 + 32 + arow_off];
      const float4 f3 = *(const float4*)&Af[(long)arow * 64 + 32 + arow_off + 4];
      a0[0] = (_Float16)f0.x; a0[1] = (_Float16)f0.y;
      a0[2] = (_Float16)f0.z; a0[3] = (_Float16)f0.w;
      a0[4] = (_Float16)f1.x; a0[5] = (_Float16)f1.y;
      a0[6] = (_Float16)f1.z; a0[7] = (_Float16)f1.w;
      a1[0] = (_Float16)f2.x; a1[1] = (_Float16)f2.y;
      a1[2] = (_Float16)f2.z; a1[3] = (_Float16)f2.w;
      a1[4] = (_Float16)f3.x; a1[5] = (_Float16)f3.y;
      a1[6] = (_Float16)f3.z; a1[7] = (_Float16)f3.w;
    } else {
      const __half* Ah = (const __half*)A;
      a0 = *(const half8*)&Ah[(long)arow * 64 + arow_off];
      a1 = *(const half8*)&Ah[(long)arow * 64 + 32 + arow_off];
    }
    f32x4 acc0 = {0.f, 0.f, 0.f, 0.f};
    f32x4 acc1 = {0.f, 0.f, 0.f, 0.f};
    f32x4 acc2 = {0.f, 0.f, 0.f, 0.f};
    f32x4 acc3 = {0.f, 0.f, 0.f, 0.f};
    acc0 = __builtin_amdgcn_mfma_f32_16x16x32_f16(a0, bfrag[0], acc0, 0, 0, 0);
    acc1 = __builtin_amdgcn_mfma_f32_16x16x32_f16(a0, bfrag[1], acc1, 0, 0, 0);
    acc2 = __builtin_amdgcn_mfma_f32_16x16x32_f16(a0, bfrag[2], acc2, 0, 0, 0);
    acc3 = __builtin_amdgcn_mfma_f32_16x16x32_f16(a0, bfrag[3], acc3, 0, 0, 0);
    acc0 = __builtin_amdgcn_mfma_f32_16x16x32_f16(a1, bfrag[4], acc0, 0, 0, 0);
    acc1 = __builtin_amdgcn_mfma_f32_16x16x32_f16(a1, bfrag[5], acc1, 0, 0, 0);
    acc2 = __builtin_amdgcn_mfma_f32_16x16x32_f16(a1, bfrag[6], acc2, 0, 0, 0);
    acc3 = __builtin_amdgcn_mfma_f32_16x16x32_f16(a1, bfrag[7], acc3, 0, 0, 0);
    const int col = lane & 15;
    const int mbase = rt + ((lane >> 4) << 2);
#pragma unroll
    for (int reg = 0; reg < 4; ++reg) {
      const int r = mbase + reg;
      if (r < N) {
        __half* o = T + (long)r * 64 + col;
        o[0]  = __float2half_rn(acc0[reg]);
        o[16] = __float2half_rn(acc1[reg]);
        o[32] = __float2half_rn(acc2[reg]);
        o[48] = __float2half_rn(acc3[reg]);
      }
    }
  }
}

#define GFMA(A0, A1, RAW, W)                                                  \
  {                                                                           \
    const __half2* hp_ = (const __half2*)&(RAW);                              \
    float2 f_;                                                                \
    f_ = __half22float2(hp_[0]); A0.x = fmaf(f_.x, W, A0.x); A0.y = fmaf(f_.y, W, A0.y); \
    f_ = __half22float2(hp_[1]); A0.z = fmaf(f_.x, W, A0.z); A0.w = fmaf(f_.y, W, A0.w); \
    f_ = __half22float2(hp_[2]); A1.x = fmaf(f_.x, W, A1.x); A1.y = fmaf(f_.y, W, A1.y); \
    f_ = __half22float2(hp_[3]); A1.z = fmaf(f_.x, W, A1.z); A1.w = fmaf(f_.y, W, A1.w); \
  }

#define BFLY8(A0, A1)                                                         \
  _Pragma("unroll") for (int m_ = 8; m_ <= 32; m_ <<= 1) {                    \
    A0.x += __shfl_xor(A0.x, m_); A0.y += __shfl_xor(A0.y, m_);               \
    A0.z += __shfl_xor(A0.z, m_); A0.w += __shfl_xor(A0.w, m_);               \
    A1.x += __shfl_xor(A1.x, m_); A1.y += __shfl_xor(A1.y, m_);               \
    A1.z += __shfl_xor(A1.z, m_); A1.w += __shfl_xor(A1.w, m_);               \
  }

// H[d][:] = relu( sum_{slots} dinv[s]*dinv[d] * T[s][:] + b )
// 2 nodes per wave iteration: two INDEPENDENT gather chains in flight
// (wave-uniform n0/n1 branches). 8 edge slots/node/round, 8-lane groups.
// __launch_bounds__(256,8) pins VGPR <= 64 to keep 32 waves/CU.
template <bool HALFOUT>
__global__ __launch_bounds__(256, 8) void k_agg(const __half* __restrict__ Th,
                                                const int2* __restrict__ meta,
                                                const int* __restrict__ csr,
                                                const float* __restrict__ dinv,
                                                const float* __restrict__ b,
                                                void* __restrict__ H, int N) {
  const int lane = threadIdx.x & 63;
  const int wid = threadIdx.x >> 6;
  const int grp = lane >> 3;   // edge slot within the round
  const int q = lane & 7;      // column group: cols 8q..8q+7
  const __half* __restrict__ Tq = Th + q * 8;
  const float4 bq0 = *(const float4*)&b[q * 8];
  const float4 bq1 = *(const float4*)&b[q * 8 + 4];
  const int stride2 = gridDim.x * 4 * 2;

  for (int d0 = (blockIdx.x * 4 + wid) * 2; d0 < N; d0 += stride2) {
    const int d1 = d0 + 1;
    const int2 mt0 = meta[d0];
    const int2 mt1 = (d1 < N) ? meta[d1] : make_int2(0, 0);
    const int n0 = mt0.x, n1 = mt1.x;
    if ((n0 | n1) == 0) continue;
    const float dv0 = __int_as_float(mt0.y);
    const float dv1 = __int_as_float(mt1.y);
    const int* __restrict__ cb0 = csr + (long)d0 * 64;
    const int* __restrict__ cb1 = csr + (long)d1 * 64;
    float4 a00 = make_float4(0.f, 0.f, 0.f, 0.f);
    float4 a01 = make_float4(0.f, 0.f, 0.f, 0.f);
    float4 a10 = make_float4(0.f, 0.f, 0.f, 0.f);
    float4 a11 = make_float4(0.f, 0.f, 0.f, 0.f);
    const int r0 = (n0 + 7) & ~7;
    const int r1 = (n1 + 7) & ~7;
    const int R = max(r0, r1);
#pragma unroll 2
    for (int i = grp; i < R; i += 8) {
      if (i < r0) {                        // wave-uniform branch
        const int idx = min(i, n0 - 1);
        const int s = cb0[idx];
        const float4 raw = *(const float4*)&Tq[(long)s * 64];
        const float w = (i < n0) ? dinv[s] * dv0 : 0.f;
        GFMA(a00, a01, raw, w);
      }
      if (i < r1) {                        // wave-uniform branch
        const int idx = min(i, n1 - 1);
        const int s = cb1[idx];
        const float4 raw = *(const float4*)&Tq[(long)s * 64];
        const float w = (i < n1) ? dinv[s] * dv1 : 0.f;
        GFMA(a10, a11, raw, w);
      }
    }
    if (n0 > 0) {
      BFLY8(a00, a01);
      if (grp == 0) {
        const float v0 = fmaxf(a00.x + bq0.x, 0.f);
        const float v1 = fmaxf(a00.y + bq0.y, 0.f);
        const float v2 = fmaxf(a00.z + bq0.z, 0.f);
        const float v3 = fmaxf(a00.w + bq0.w, 0.f);
        const float v4 = fmaxf(a01.x + bq1.x, 0.f);
        const float v5 = fmaxf(a01.y + bq1.y, 0.f);
        const float v6 = fmaxf(a01.z + bq1.z, 0.f);
        const float v7 = fmaxf(a01.w + bq1.w, 0.f);
        if (HALFOUT) {
          __half2* o = (__half2*)((__half*)H + (long)d0 * 64 + q * 8);
          o[0] = __floats2half2_rn(v0, v1);
          o[1] = __floats2half2_rn(v2, v3);
          o[2] = __floats2half2_rn(v4, v5);
          o[3] = __floats2half2_rn(v6, v7);
        } else {
          float* o = (float*)H + (long)d0 * 64 + q * 8;
          *(float4*)o = make_float4(v0, v1, v2, v3);
          *(float4*)(o + 4) = make_float4(v4, v5, v6, v7);
        }
      }
    }
    if (n1 > 0) {
      BFLY8(a10, a11);
      if (grp == 0) {
        const float v0 = fmaxf(a10.x + bq0.x, 0.f);
        const float v1 = fmaxf(a10.y + bq0.y, 0.f);
        const float v2 = fmaxf(a10.z + bq0.z, 0.f);
        const float v3 = fmaxf(a10.w + bq0.w, 0.f);
        const float v4 = fmaxf(a11.x + bq1.x, 0.f);
        const float v5 = fmaxf(a11.y + bq1.y, 0.f);
        const float v6 = fmaxf(a11.z + bq1.z, 0.f);
        const float v7 = fmaxf(a11.w + bq1.w, 0.f);
        if (HALFOUT) {
          __half2* o = (__half2*)((__half*)H + (long)d1 * 64 + q * 8);
          o[0] = __floats2half2_rn(v0, v1);
          o[1] = __floats2half2_rn(v2, v3);
          o[2] = __floats2half2_rn(v4, v5);
          o[3] = __floats2half2_rn(v6, v7);
        } else {
          float* o = (float*)H + (long)d1 * 64 + q * 8;
          *(float4*)o = make_float4(v0, v1, v2, v3);
          *(float4*)(o + 4) = make_float4(v4, v5, v6, v7);
        }
      }
    }
  }
}

// Fused: per-graph max-pool over kept nodes -> MLP head -> out[grp][:]
__global__ __launch_bounds__(256) void k_pool_head(
    const float* __restrict__ H, const float* __restrict__ maskf,
    const int* __restrict__ gs, const int* __restrict__ ge,
    const float* __restrict__ fw1, const float* __restrict__ fb1,
    const float* __restrict__ fw2, const float* __restrict__ fb2,
    float* __restrict__ out, int N, int C) {
  __shared__ float sP[4][64];
  __shared__ float sg[64];
  __shared__ float sg2[64];
  const int grp = blockIdx.x;
  const int lane = threadIdx.x & 63, wid = threadIdx.x >> 6;
  const int s = gs[grp], e = ge[grp];
  float v = 0.f;
  if (s <= e) {
    for (int i = s + wid; i <= e; i += 4)
      if (maskf[i] != 0.f) v = fmaxf(v, H[(long)i * 64 + lane]);
  }
  sP[wid][lane] = v;
  __syncthreads();
  if (wid == 0)
    sg[lane] = fmaxf(fmaxf(sP[0][lane], sP[1][lane]), fmaxf(sP[2][lane], sP[3][lane]));
  __syncthreads();
  if (threadIdx.x < 64) {
    const int f = threadIdx.x;
    float acc = fb1[f];
#pragma unroll 8
    for (int k = 0; k < 64; ++k) acc = fmaf(sg[k], fw1[k * 64 + f], acc);
    sg2[f] = fmaxf(acc, 0.f);
  }
  __syncthreads();
  if (threadIdx.x < C) {
    const int c = threadIdx.x;
    float acc = fb2[c];
#pragma unroll 8
    for (int k = 0; k < 64; ++k) acc = fmaf(sg2[k], fw2[k * C + c], acc);
    out[grp * C + c] = acc;
  }
}

extern "C" void kernel_launch(void* const* d_in, const int* in_sizes, int n_in,
                              void* d_out, int out_size, void* d_ws, size_t ws_size,
                              hipStream_t stream) {
  const float* x    = (const float*)d_in[0];
  const int*   ei   = (const int*)d_in[1];
  const int*   batch= (const int*)d_in[2];
  const void*  mraw = d_in[3];
  const float* W1   = (const float*)d_in[4];
  const float* b1   = (const float*)d_in[5];
  const float* W2   = (const float*)d_in[6];
  const float* b2   = (const float*)d_in[7];
  const float* W3   = (const float*)d_in[8];
  const float* b3   = (const float*)d_in[9];
  const float* fw1  = (const float*)d_in[10];
  const float* fb1  = (const float*)d_in[11];
  const float* fw2  = (const float*)d_in[12];
  const float* fb2  = (const float*)d_in[13];
  float* out = (float*)d_out;

  const int N = in_sizes[0] / 64;
  const int E = in_sizes[1] / 2;
  const int C = in_sizes[13];
  const int* src = ei;
  const int* dst = ei + E;
  const int G = out_size / C;

  char* ws = (char*)d_ws;
  size_t off_b = 0;
  auto alloc = [&](size_t bytes) -> void* {
    void* p = ws + off_b;
    off_b += (bytes + 255) & ~(size_t)255;
    return p;
  };
  int*    flag   = (int*)alloc(sizeof(int));
  float*  maskf  = (float*)alloc((size_t)N * 4);
  int*    cnt    = (int*)alloc((size_t)N * 4);
  float*  dinv   = (float*)alloc((size_t)N * 4);
  int2*   meta   = (int2*)alloc((size_t)N * 8);
  int*    gs     = (int*)alloc((size_t)G * 4);
  int*    ge     = (int*)alloc((size_t)G * 4);
  int*    csr    = (int*)alloc((size_t)N * 64 * 4);   // 64 slots/node
  __half* Wsw    = (__half*)alloc(3 * 4096 * 2);
  __half* T      = (__half*)alloc((size_t)N * 64 * 2);
  __half* H1h    = (__half*)alloc((size_t)N * 64 * 2);
  __half* H2h    = (__half*)alloc((size_t)N * 64 * 2);
  float*  H3     = (float*)alloc((size_t)N * 64 * 4);
  (void)ws_size;

  const int nb = (N + 255) / 256;

  k_detect<<<1, 1024, 0, stream>>>((const unsigned int*)mraw, N / 4, flag);
  k_prep<<<nb, 256, 0, stream>>>(mraw, flag, maskf, cnt, gs, ge,
                                 W1, W2, W3, Wsw, N, G);

  const int gemm_blocks = 512;
  const int agg_blocks = 2048;

  // layer-1 GEMM first: depends only on prep (x read directly as f32)
  k_gemm_mfma<true><<<gemm_blocks, 256, 0, stream>>>(x, Wsw, T, N);

  k_fill<<<(E / 2 + 255) / 256, 256, 0, stream>>>(src, dst, maskf, cnt, csr, E);
  k_dinvself<<<nb, 256, 0, stream>>>(cnt, maskf, dinv, meta, csr, batch, gs, ge, N);

  // layer 1 aggregate
  k_agg<true><<<agg_blocks, 256, 0, stream>>>(T, meta, csr, dinv, b1, H1h, N);
  // layer 2
  k_gemm_mfma<false><<<gemm_blocks, 256, 0, stream>>>(H1h, Wsw + 4096, T, N);
  k_agg<true><<<agg_blocks, 256, 0, stream>>>(T, meta, csr, dinv, b2, H2h, N);
  // layer 3
  k_gemm_mfma<false><<<gemm_blocks, 256, 0, stream>>>(H2h, Wsw + 8192, T, N);
  k_agg<false><<<agg_blocks, 256, 0, stream>>>(T, meta, csr, dinv, b3, H3, N);

  k_pool_head<<<G, 256, 0, stream>>>(H3, maskf, gs, ge, fw1, fb1, fw2, fb2, out, N, C);
}

// Round 17
// 143.789 us; speedup vs baseline: 1.3893x; 1.0213x over previous
//
#include <hip/hip_runtime.h>
#include <hip/hip_fp16.h>

// ---------------------------------------------------------------------------
// GCN pipeline v17: v14 base + software-pipelined agg (next node's meta+CSR
// bucket prefetched into registers; slots broadcast via shfl). 11 dispatches.
// N=50000 nodes, E=800000 edges, H=F=64, G=512 graphs, C=10 classes
// ---------------------------------------------------------------------------

using half8 = __attribute__((ext_vector_type(8))) _Float16;
using f32x4 = __attribute__((ext_vector_type(4))) float;

// Single-block: detect whether mask is bytes (some word >1) or int32 0/1.
__global__ void k_detect(const unsigned int* __restrict__ m, int n_ints,
                         int* __restrict__ flag) {
  __shared__ int found;
  if (threadIdx.x == 0) found = 0;
  __syncthreads();
  int loc = 0;
  for (int i = threadIdx.x; i < n_ints; i += blockDim.x)
    if (m[i] > 1u) loc = 1;
  if (loc) found = 1;
  __syncthreads();
  if (threadIdx.x == 0) *flag = found;
}

// maskf + zero cnt + init gs/ge + W1/2/3 -> MFMA-swizzled fp16 fragments.
__global__ void k_prep(const void* __restrict__ mraw, const int* __restrict__ flag,
                       float* __restrict__ maskf, int* __restrict__ cnt,
                       int* __restrict__ gs, int* __restrict__ ge,
                       const float* __restrict__ W1, const float* __restrict__ W2,
                       const float* __restrict__ W3, __half* __restrict__ Wsw,
                       int N, int G) {
  int idx = blockIdx.x * blockDim.x + threadIdx.x;
  if (idx < 3 * 4096) {
    const int layer = idx >> 12;
    const int rem = idx & 4095;
    const int f = rem >> 9;
    const int l = (rem >> 3) & 63;
    const int j = rem & 7;
    const int k = (f >> 2) * 32 + ((l >> 4) << 3) + j;
    const int c = ((f & 3) << 4) + (l & 15);
    const float* Wl = (layer == 0) ? W1 : (layer == 1) ? W2 : W3;
    Wsw[idx] = __float2half_rn(Wl[k * 64 + c]);
  }
  if (idx < G) { gs[idx] = 0x7fffffff; ge[idx] = -1; }
  if (idx < N) {
    float v;
    if (*flag) v = (float)((const unsigned char*)mraw)[idx];
    else       v = (float)((const int*)mraw)[idx];
    maskf[idx] = v;
    cnt[idx] = 0;
  }
}

// One-pass bucket CSR, 2 edges/thread: csr[d*64 + slot] = s.
__global__ void k_fill(const int* __restrict__ src, const int* __restrict__ dst,
                       const float* __restrict__ maskf, int* __restrict__ cnt,
                       int* __restrict__ csr, int E) {
  int e2 = blockIdx.x * blockDim.x + threadIdx.x;
  int e = e2 * 2;
  if (e >= E) return;
  if (e + 1 < E) {
    const int2 s2 = *(const int2*)&src[e];
    const int2 d2 = *(const int2*)&dst[e];
    if (maskf[s2.x] != 0.f && maskf[d2.x] != 0.f) {
      int p = atomicAdd(&cnt[d2.x], 1);
      if (p < 63) csr[(long)d2.x * 64 + p] = s2.x;
    }
    if (maskf[s2.y] != 0.f && maskf[d2.y] != 0.f) {
      int p = atomicAdd(&cnt[d2.y], 1);
      if (p < 63) csr[(long)d2.y * 64 + p] = s2.y;
    }
  } else {
    const int s = src[e], d = dst[e];
    if (maskf[s] != 0.f && maskf[d] != 0.f) {
      int p = atomicAdd(&cnt[d], 1);
      if (p < 63) csr[(long)d * 64 + p] = s;
    }
  }
}

// dinv + self-loop slot + meta=(n, dinv_bits) + per-graph bounds (sorted batch).
__global__ void k_dinvself(const int* __restrict__ cnt, const float* __restrict__ maskf,
                           float* __restrict__ dinv, int2* __restrict__ meta,
                           int* __restrict__ csr, const int* __restrict__ batch,
                           int* __restrict__ gs, int* __restrict__ ge, int N) {
  int i = blockIdx.x * blockDim.x + threadIdx.x;
  if (i >= N) return;
  int c = min(cnt[i], 63);
  float mk = maskf[i];
  float dsum = (float)c + mk;
  float di = (dsum > 0.f) ? rsqrtf(dsum) : 0.f;
  dinv[i] = di;
  int n;
  if (mk != 0.f) {
    csr[(long)i * 64 + c] = i;   // self-loop entry
    n = c + 1;
  } else {
    n = 0;
  }
  meta[i] = make_int2(n, __float_as_int(di));
  int b = batch[i];
  if (i == 0 || batch[i - 1] != b) gs[b] = i;
  if (i == N - 1 || batch[i + 1] != b) ge[b] = i;
}

// T = A @ W via MFMA 16x16x32 fp16. Wave per 16-row tile (grid-stride).
template <bool F32IN>
__global__ __launch_bounds__(256) void k_gemm_mfma(const void* __restrict__ A,
                                                   const __half* __restrict__ Wsw,
                                                   __half* __restrict__ T, int N) {
  const int lane = threadIdx.x & 63;
  const int wid = threadIdx.x >> 6;
  half8 bfrag[8];
#pragma unroll
  for (int f = 0; f < 8; ++f)
    bfrag[f] = *(const half8*)&Wsw[f * 512 + lane * 8];
  const int tiles = (N + 15) >> 4;
  const int arow_off = ((lane >> 4) << 3);
  for (int t = blockIdx.x * 4 + wid; t < tiles; t += gridDim.x * 4) {
    const int rt = t << 4;
    int arow = rt + (lane & 15);
    if (arow >= N) arow = N - 1;
    half8 a0, a1;
    if (F32IN) {
      const float* Af = (const float*)A;
      const float4 f0 = *(const float4*)&Af[(long)arow * 64 + arow_off];
      const float4 f1 = *(const float4*)&Af[(long)arow * 64 + arow_off + 4];
      const float4 f2 = *(const float4*)&Af[(long)arow * 64 + 32 + arow_off];
      const float4 f3 = *(const float4*)&Af[(long)arow * 64 + 32 + arow_off + 4];
      a0[0] = (_Float16)f0.x; a0[1] = (_Float16)f0.y;
      a0[2] = (_Float16)f0.z; a0[3] = (_Float16)f0.w;
      a0[4] = (_Float16)f1.x; a0[5] = (_Float16)f1.y;
      a0[6] = (_Float16)f1.z; a0[7] = (_Float16)f1.w;
      a1[0] = (_Float16)f2.x; a1[1] = (_Float16)f2.y;
      a1[2] = (_Float16)f2.z; a1[3] = (_Float16)f2.w;
      a1[4] = (_Float16)f3.x; a1[5] = (_Float16)f3.y;
      a1[6] = (_Float16)f3.z; a1[7] = (_Float16)f3.w;
    } else {
      const __half* Ah = (const __half*)A;
      a0 = *(const half8*)&Ah[(long)arow * 64 + arow_off];
      a1 = *(const half8*)&Ah[(long)arow * 64 + 32 + arow_off];
    }
    f32x4 acc0 = {0.f, 0.f, 0.f, 0.f};
    f32x4 acc1 = {0.f, 0.f, 0.f, 0.f};
    f32x4 acc2 = {0.f, 0.f, 0.f, 0.f};
    f32x4 acc3 = {0.f, 0.f, 0.f, 0.f};
    acc0 = __builtin_amdgcn_mfma_f32_16x16x32_f16(a0, bfrag[0], acc0, 0, 0, 0);
    acc1 = __builtin_amdgcn_mfma_f32_16x16x32_f16(a0, bfrag[1], acc1, 0, 0, 0);
    acc2 = __builtin_amdgcn_mfma_f32_16x16x32_f16(a0, bfrag[2], acc2, 0, 0, 0);
    acc3 = __builtin_amdgcn_mfma_f32_16x16x32_f16(a0, bfrag[3], acc3, 0, 0, 0);
    acc0 = __builtin_amdgcn_mfma_f32_16x16x32_f16(a1, bfrag[4], acc0, 0, 0, 0);
    acc1 = __builtin_amdgcn_mfma_f32_16x16x32_f16(a1, bfrag[5], acc1, 0, 0, 0);
    acc2 = __builtin_amdgcn_mfma_f32_16x16x32_f16(a1, bfrag[6], acc2, 0, 0, 0);
    acc3 = __builtin_amdgcn_mfma_f32_16x16x32_f16(a1, bfrag[7], acc3, 0, 0, 0);
    const int col = lane & 15;
    const int mbase = rt + ((lane >> 4) << 2);
#pragma unroll
    for (int reg = 0; reg < 4; ++reg) {
      const int r = mbase + reg;
      if (r < N) {
        __half* o = T + (long)r * 64 + col;
        o[0]  = __float2half_rn(acc0[reg]);
        o[16] = __float2half_rn(acc1[reg]);
        o[32] = __float2half_rn(acc2[reg]);
        o[48] = __float2half_rn(acc3[reg]);
      }
    }
  }
}

#define GFMA(A0, A1, RAW, W)                                                  \
  {                                                                           \
    const __half2* hp_ = (const __half2*)&(RAW);                              \
    float2 f_;                                                                \
    f_ = __half22float2(hp_[0]); A0.x = fmaf(f_.x, W, A0.x); A0.y = fmaf(f_.y, W, A0.y); \
    f_ = __half22float2(hp_[1]); A0.z = fmaf(f_.x, W, A0.z); A0.w = fmaf(f_.y, W, A0.w); \
    f_ = __half22float2(hp_[2]); A1.x = fmaf(f_.x, W, A1.x); A1.y = fmaf(f_.y, W, A1.y); \
    f_ = __half22float2(hp_[3]); A1.z = fmaf(f_.x, W, A1.z); A1.w = fmaf(f_.y, W, A1.w); \
  }

#define BFLY8(A0, A1)                                                         \
  _Pragma("unroll") for (int m_ = 8; m_ <= 32; m_ <<= 1) {                    \
    A0.x += __shfl_xor(A0.x, m_); A0.y += __shfl_xor(A0.y, m_);               \
    A0.z += __shfl_xor(A0.z, m_); A0.w += __shfl_xor(A0.w, m_);               \
    A1.x += __shfl_xor(A1.x, m_); A1.y += __shfl_xor(A1.y, m_);               \
    A1.z += __shfl_xor(A1.z, m_); A1.w += __shfl_xor(A1.w, m_);               \
  }

// H[d][:] = relu( sum_{slots} dinv[s]*dinv[d] * T[s][:] + b )
// Software-pipelined: while processing node d, the NEXT node's meta and whole
// 64-slot CSR bucket (one coalesced 256B wave-load into 1 VGPR/lane) are
// already in flight. Slots broadcast via shfl. 8 edge slots/round.
template <bool HALFOUT>
__global__ __launch_bounds__(256, 8) void k_agg(const __half* __restrict__ Th,
                                                const int2* __restrict__ meta,
                                                const int* __restrict__ csr,
                                                const float* __restrict__ dinv,
                                                const float* __restrict__ b,
                                                void* __restrict__ H, int N) {
  const int lane = threadIdx.x & 63;
  const int wid = threadIdx.x >> 6;
  const int grp = lane >> 3;   // edge slot within the round
  const int q = lane & 7;      // column group: cols 8q..8q+7
  const __half* __restrict__ Tq = Th + q * 8;
  const float4 bq0 = *(const float4*)&b[q * 8];
  const float4 bq1 = *(const float4*)&b[q * 8 + 4];
  const int stride = gridDim.x * 4;

  int d = blockIdx.x * 4 + wid;
  if (d >= N) return;
  // prologue: current node's meta + CSR bucket
  int2 mt_c = meta[d];
  int cv_c = csr[(long)d * 64 + lane];

  while (d < N) {
    const int dn = d + stride;
    // prefetch next node (no dependency on current processing)
    int2 mt_n = make_int2(0, 0);
    int cv_n = 0;
    if (dn < N) {
      mt_n = meta[dn];
      cv_n = csr[(long)dn * 64 + lane];
    }
    const int n = mt_c.x;
    if (n > 0) {
      const float dv = __int_as_float(mt_c.y);
      float4 a0 = make_float4(0.f, 0.f, 0.f, 0.f);
      float4 a1 = make_float4(0.f, 0.f, 0.f, 0.f);
      const int rounds = (n + 7) & ~7;
#pragma unroll 2
      for (int i = grp; i < rounds; i += 8) {
        const int idx = min(i, n - 1);    // clamp: padded slots re-read last
        const int s = __shfl(cv_c, idx);
        const float4 raw = *(const float4*)&Tq[(long)s * 64];
        const float w = (i < n) ? dinv[s] * dv : 0.f;
        GFMA(a0, a1, raw, w);
      }
      BFLY8(a0, a1);
      if (grp == 0) {
        const float v0 = fmaxf(a0.x + bq0.x, 0.f);
        const float v1 = fmaxf(a0.y + bq0.y, 0.f);
        const float v2 = fmaxf(a0.z + bq0.z, 0.f);
        const float v3 = fmaxf(a0.w + bq0.w, 0.f);
        const float v4 = fmaxf(a1.x + bq1.x, 0.f);
        const float v5 = fmaxf(a1.y + bq1.y, 0.f);
        const float v6 = fmaxf(a1.z + bq1.z, 0.f);
        const float v7 = fmaxf(a1.w + bq1.w, 0.f);
        if (HALFOUT) {
          __half2* o = (__half2*)((__half*)H + (long)d * 64 + q * 8);
          o[0] = __floats2half2_rn(v0, v1);
          o[1] = __floats2half2_rn(v2, v3);
          o[2] = __floats2half2_rn(v4, v5);
          o[3] = __floats2half2_rn(v6, v7);
        } else {
          float* o = (float*)H + (long)d * 64 + q * 8;
          *(float4*)o = make_float4(v0, v1, v2, v3);
          *(float4*)(o + 4) = make_float4(v4, v5, v6, v7);
        }
      }
    }
    d = dn;
    mt_c = mt_n;
    cv_c = cv_n;
  }
}

// Fused: per-graph max-pool over kept nodes -> MLP head -> out[grp][:]
__global__ __launch_bounds__(256) void k_pool_head(
    const float* __restrict__ H, const float* __restrict__ maskf,
    const int* __restrict__ gs, const int* __restrict__ ge,
    const float* __restrict__ fw1, const float* __restrict__ fb1,
    const float* __restrict__ fw2, const float* __restrict__ fb2,
    float* __restrict__ out, int N, int C) {
  __shared__ float sP[4][64];
  __shared__ float sg[64];
  __shared__ float sg2[64];
  const int grp = blockIdx.x;
  const int lane = threadIdx.x & 63, wid = threadIdx.x >> 6;
  const int s = gs[grp], e = ge[grp];
  float v = 0.f;
  if (s <= e) {
    for (int i = s + wid; i <= e; i += 4)
      if (maskf[i] != 0.f) v = fmaxf(v, H[(long)i * 64 + lane]);
  }
  sP[wid][lane] = v;
  __syncthreads();
  if (wid == 0)
    sg[lane] = fmaxf(fmaxf(sP[0][lane], sP[1][lane]), fmaxf(sP[2][lane], sP[3][lane]));
  __syncthreads();
  if (threadIdx.x < 64) {
    const int f = threadIdx.x;
    float acc = fb1[f];
#pragma unroll 8
    for (int k = 0; k < 64; ++k) acc = fmaf(sg[k], fw1[k * 64 + f], acc);
    sg2[f] = fmaxf(acc, 0.f);
  }
  __syncthreads();
  if (threadIdx.x < C) {
    const int c = threadIdx.x;
    float acc = fb2[c];
#pragma unroll 8
    for (int k = 0; k < 64; ++k) acc = fmaf(sg2[k], fw2[k * C + c], acc);
    out[grp * C + c] = acc;
  }
}

extern "C" void kernel_launch(void* const* d_in, const int* in_sizes, int n_in,
                              void* d_out, int out_size, void* d_ws, size_t ws_size,
                              hipStream_t stream) {
  const float* x    = (const float*)d_in[0];
  const int*   ei   = (const int*)d_in[1];
  const int*   batch= (const int*)d_in[2];
  const void*  mraw = d_in[3];
  const float* W1   = (const float*)d_in[4];
  const float* b1   = (const float*)d_in[5];
  const float* W2   = (const float*)d_in[6];
  const float* b2   = (const float*)d_in[7];
  const float* W3   = (const float*)d_in[8];
  const float* b3   = (const float*)d_in[9];
  const float* fw1  = (const float*)d_in[10];
  const float* fb1  = (const float*)d_in[11];
  const float* fw2  = (const float*)d_in[12];
  const float* fb2  = (const float*)d_in[13];
  float* out = (float*)d_out;

  const int N = in_sizes[0] / 64;
  const int E = in_sizes[1] / 2;
  const int C = in_sizes[13];
  const int* src = ei;
  const int* dst = ei + E;
  const int G = out_size / C;

  char* ws = (char*)d_ws;
  size_t off_b = 0;
  auto alloc = [&](size_t bytes) -> void* {
    void* p = ws + off_b;
    off_b += (bytes + 255) & ~(size_t)255;
    return p;
  };
  int*    flag   = (int*)alloc(sizeof(int));
  float*  maskf  = (float*)alloc((size_t)N * 4);
  int*    cnt    = (int*)alloc((size_t)N * 4);
  float*  dinv   = (float*)alloc((size_t)N * 4);
  int2*   meta   = (int2*)alloc((size_t)N * 8);
  int*    gs     = (int*)alloc((size_t)G * 4);
  int*    ge     = (int*)alloc((size_t)G * 4);
  int*    csr    = (int*)alloc((size_t)N * 64 * 4);   // 64 slots/node
  __half* Wsw    = (__half*)alloc(3 * 4096 * 2);
  __half* T      = (__half*)alloc((size_t)N * 64 * 2);
  __half* H1h    = (__half*)alloc((size_t)N * 64 * 2);
  __half* H2h    = (__half*)alloc((size_t)N * 64 * 2);
  float*  H3     = (float*)alloc((size_t)N * 64 * 4);
  (void)ws_size;

  const int nb = (N + 255) / 256;

  k_detect<<<1, 1024, 0, stream>>>((const unsigned int*)mraw, N / 4, flag);
  k_prep<<<nb, 256, 0, stream>>>(mraw, flag, maskf, cnt, gs, ge,
                                 W1, W2, W3, Wsw, N, G);

  const int gemm_blocks = 512;
  const int agg_blocks = 2048;

  // layer-1 GEMM first: depends only on prep (x read directly as f32)
  k_gemm_mfma<true><<<gemm_blocks, 256, 0, stream>>>(x, Wsw, T, N);

  k_fill<<<(E / 2 + 255) / 256, 256, 0, stream>>>(src, dst, maskf, cnt, csr, E);
  k_dinvself<<<nb, 256, 0, stream>>>(cnt, maskf, dinv, meta, csr, batch, gs, ge, N);

  // layer 1 aggregate
  k_agg<true><<<agg_blocks, 256, 0, stream>>>(T, meta, csr, dinv, b1, H1h, N);
  // layer 2
  k_gemm_mfma<false><<<gemm_blocks, 256, 0, stream>>>(H1h, Wsw + 4096, T, N);
  k_agg<true><<<agg_blocks, 256, 0, stream>>>(T, meta, csr, dinv, b2, H2h, N);
  // layer 3
  k_gemm_mfma<false><<<gemm_blocks, 256, 0, stream>>>(H2h, Wsw + 8192, T, N);
  k_agg<false><<<agg_blocks, 256, 0, stream>>>(T, meta, csr, dinv, b3, H3, N);

  k_pool_head<<<G, 256, 0, stream>>>(H3, maskf, gs, ge, fw1, fb1, fw2, fb2, out, N, C);
}